// Round 9
// baseline (48.971 us; speedup 1.0000x reference)
//
#include <hip/hip_runtime.h>

typedef unsigned short ushort_t;
typedef unsigned int uint_t;
typedef short short8 __attribute__((ext_vector_type(8)));
typedef float f32x4 __attribute__((ext_vector_type(4)));

namespace {

template<int CTRL, int RM>
__device__ __forceinline__ float dpp_mov0(float v) {
  return __int_as_float(__builtin_amdgcn_update_dpp(
      0, __float_as_int(v), CTRL, RM, 0xF, false));
}
template<int CTRL, int RM>
__device__ __forceinline__ float dpp_mov1(float v) {
  return __int_as_float(__builtin_amdgcn_update_dpp(
      0x3f800000, __float_as_int(v), CTRL, RM, 0xF, false));
}

__device__ __forceinline__ float rl(float v, int k) {
  return __int_as_float(__builtin_amdgcn_readlane(__float_as_int(v), k));
}

// lhs = I - h*A = diag(d_n) + h r_i r_k (k<i), h=dt/2, r_n=sqrt(2n+1),
// d_n=1+h(n+1). y = A_bar x via one joint 2-var linear-recurrence DPP scan
// (HW-verified rounds 1-8, absmax <= 4.9e-4). Coefs hoisted.
struct Hoist {
  float cs0, cs1, cs2, cs3, cs4, cs5;
  float gs0, gs1, gs2, gs3, gs4, gs5;
  float r, inv_d, hr, alpha, k2;
};

__device__ __forceinline__ Hoist make_hoist(float dt, int n) {
  float h = 0.5f * dt, fn = (float)n;
  float r = sqrtf(2.f * fn + 1.f);
  float d = 1.f + h * (fn + 1.f);
  float inv_d = 1.f / d;
  float g = (1.f - h * fn) * inv_d;
  float c = g - 1.f;                  // = -h r^2 / d
  Hoist H;
  H.r = r; H.inv_d = inv_d; H.hr = h * r;
  H.alpha = 1.f + h * fn;
  H.k2 = r * (2.f - d) * inv_d;
#define COEF_STEP(IDX, CTRL, RM)                                        \
  H.cs##IDX = c; H.gs##IDX = g;                                         \
  { float cP = dpp_mov0<CTRL, RM>(c);                                   \
    float gP = dpp_mov1<CTRL, RM>(g);                                   \
    c = fmaf(g, cP, c); g = g * gP; }
  COEF_STEP(0, 0x111, 0xF)   // row_shr:1
  COEF_STEP(1, 0x112, 0xF)   // row_shr:2
  COEF_STEP(2, 0x114, 0xF)   // row_shr:4
  COEF_STEP(3, 0x118, 0xF)   // row_shr:8
  COEF_STEP(4, 0x142, 0xA)   // row_bcast15 -> rows 1,3
  COEF_STEP(5, 0x143, 0xC)   // row_bcast31 -> rows 2,3
#undef COEF_STEP
  return H;
}

__device__ __forceinline__ float abar_apply(float x, const Hoist& H) {
  float w1 = H.r * x, w2 = H.k2 * x;
#define APPLY_STEP(IDX, CTRL, RM)                                       \
  { float w1P = dpp_mov0<CTRL, RM>(w1);                                 \
    float w2P = dpp_mov0<CTRL, RM>(w2);                                 \
    w2 = fmaf(H.cs##IDX, w1P, fmaf(H.gs##IDX, w2P, w2));                \
    w1 += w1P; }
  APPLY_STEP(0, 0x111, 0xF)
  APPLY_STEP(1, 0x112, 0xF)
  APPLY_STEP(2, 0x114, 0xF)
  APPLY_STEP(3, 0x118, 0xF)
  APPLY_STEP(4, 0x142, 0xA)
  APPLY_STEP(5, 0x143, 0xC)
#undef APPLY_STEP
  float tp = dpp_mov0<0x138, 0xF>(w2);           // wave_shr:1 -> T_{i-1}
  return H.inv_d * fmaf(-H.hr, w1 + tp, H.alpha * x);
}

template<int CTRL, int RM>
__device__ __forceinline__ void linrec_step(float& G, float& W) {
  float Wo = dpp_mov0<CTRL, RM>(W);
  float Go = dpp_mov1<CTRL, RM>(G);
  W = fmaf(G, Wo, W);
  G *= Go;
}
__device__ __forceinline__ float lhs_solve(float z, const Hoist& H) {
  float G = H.gs0, W = H.r * z * H.inv_d;
  linrec_step<0x111, 0xF>(G, W);
  linrec_step<0x112, 0xF>(G, W);
  linrec_step<0x114, 0xF>(G, W);
  linrec_step<0x118, 0xF>(G, W);
  linrec_step<0x142, 0xA>(G, W);
  linrec_step<0x143, 0xC>(G, W);
  float sp = dpp_mov0<0x138, 0xF>(W);
  return (z - H.hr * sp) * H.inv_d;
}

__device__ __forceinline__ float softplus_dt(float ldt) {
  return log1pf(expf(ldt)) + 1e-6f;
}

// pc[k] = M[lane][k] from global (L2-hot) into registers. VMEM only.
__device__ __forceinline__ void load_row_g(const float* __restrict__ base,
                                           float (&pc)[64]) {
  const float4* p4 = (const float4*)base;
  #pragma unroll
  for (int q = 0; q < 16; ++q) {
    float4 f = p4[q];
    pc[4*q+0] = f.x; pc[4*q+1] = f.y; pc[4*q+2] = f.z; pc[4*q+3] = f.w;
  }
}

// res[lane] = sum_k pc[k]*u[k]; u distributed, broadcast via readlane.
__device__ __forceinline__ float qapply(const float (&pc)[64], float u) {
  float a0 = 0.f, a1 = 0.f, a2 = 0.f, a3 = 0.f;
  #pragma unroll
  for (int k = 0; k < 64; k += 4) {
    a0 = fmaf(pc[k + 0], rl(u, k + 0), a0);
    a1 = fmaf(pc[k + 1], rl(u, k + 1), a1);
    a2 = fmaf(pc[k + 2], rl(u, k + 2), a2);
    a3 = fmaf(pc[k + 3], rl(u, k + 3), a3);
  }
  return (a0 + a1) + (a2 + a3);
}

// streaming matvec from global row (one float4 live at a time)
__device__ __forceinline__ float grow_matvec(const float* __restrict__ M,
                                             float u, int lane) {
  float a0 = 0.f, a1 = 0.f, a2 = 0.f, a3 = 0.f;
  const float4* m4 = (const float4*)(M + lane * 64);
  #pragma unroll
  for (int q = 0; q < 16; ++q) {
    float4 f = m4[q];
    a0 = fmaf(f.x, rl(u, 4 * q + 0), a0);
    a1 = fmaf(f.y, rl(u, 4 * q + 1), a1);
    a2 = fmaf(f.z, rl(u, 4 * q + 2), a2);
    a3 = fmaf(f.w, rl(u, 4 * q + 3), a3);
  }
  return (a0 + a1) + (a2 + a3);
}

// bf16 error-compensated split store into chunk-XOR-swizzled LDS.
// Logical chunk (n>>3) of row `row` lives at phys chunk (n>>3)^(row&7).
__device__ __forceinline__ void split_store(float v, ushort_t* Hi,
                                            ushort_t* Lo, int row, int n) {
  uint_t uv = __float_as_uint(v);
  float hf = __uint_as_float(uv & 0xFFFF0000u);        // truncated hi
  uint_t lv = __float_as_uint(v - hf);                 // exact residual
  int idx = (row << 6) | (((n >> 3) ^ (row & 7)) << 3) | (n & 7);
  Hi[idx] = (ushort_t)(uv >> 16);
  Lo[idx] = (ushort_t)(lv >> 16);
}

__device__ __forceinline__ int frag_off(int row, int chunk) {
  return (row << 6) | ((chunk ^ (row & 7)) << 3);
}

} // namespace

// Prep 1: block m chains e_m through 128 applies, snapshotting:
//   s=16/32/48: col m of A^s  -> row-major S16/S32/S48 [n][k] (scatter)
//   s=64 : Q-row m  (QROW[m][k] = A^64[k][m])   coalesced
//   s=128: Q2-row m (Q2ROW[m][k] = A^128[k][m]) coalesced
__global__ __launch_bounds__(64) void hippo_pow(const float* __restrict__ ldt_p,
                                                float* __restrict__ S16,
                                                float* __restrict__ S32,
                                                float* __restrict__ S48,
                                                float* __restrict__ QROW,
                                                float* __restrict__ Q2ROW) {
  const int lane = threadIdx.x;
  const int m = blockIdx.x;
  const float dt = softplus_dt(ldt_p[0]);
  const Hoist H = make_hoist(dt, lane);
  float x = (lane == m) ? 1.f : 0.f;
  #pragma unroll 1
  for (int s = 0; s < 16; ++s) x = abar_apply(x, H);
  S16[lane * 64 + m] = x;
  #pragma unroll 1
  for (int s = 0; s < 16; ++s) x = abar_apply(x, H);
  S32[lane * 64 + m] = x;
  #pragma unroll 1
  for (int s = 0; s < 16; ++s) x = abar_apply(x, H);
  S48[lane * 64 + m] = x;
  #pragma unroll 1
  for (int s = 0; s < 16; ++s) x = abar_apply(x, H);
  QROW[m * 64 + lane] = x;
  #pragma unroll 1
  for (int s = 0; s < 64; ++s) x = abar_apply(x, H);
  Q2ROW[m * 64 + lane] = x;
}

// Prep 2: Q3ROW[n][k] = A^192[k][n], Q4ROW[n][k] = A^256[k][n].
//   Q3ROW[n][k] = sum_p QROW[n][p]  * Q2ROW[p][k]
//   Q4ROW[n][k] = sum_p Q2ROW[n][p] * Q2ROW[p][k]   (shared load stream)
__global__ __launch_bounds__(64) void hippo_qx(const float* __restrict__ QROW,
                                               const float* __restrict__ Q2ROW,
                                               float* __restrict__ Q3ROW,
                                               float* __restrict__ Q4ROW) {
  const int lane = threadIdx.x;
  const int n = blockIdx.x;
  const float u1 = QROW[n * 64 + lane];
  const float u2 = Q2ROW[n * 64 + lane];
  float a3 = 0.f, a4 = 0.f;
  #pragma unroll 4
  for (int p = 0; p < 64; ++p) {
    float val = Q2ROW[p * 64 + lane];
    a3 = fmaf(rl(u1, p), val, a3);
    a4 = fmaf(rl(u2, p), val, a4);
  }
  Q3ROW[n * 64 + lane] = a3;
  Q4ROW[n * 64 + lane] = a4;
}

// Main: per d, 8 waves, 8 balanced roles.
//  waves 0-3: V chains of 16 (seeds Bb, A16*Bb, A32*Bb, A48*Bb)
//  waves 4-7: U chains mod 4 (seeds C, Q*C, Q2*C, Q3*C; step Q4), 8 rows each
//  Epilogue: one 16x16 MFMA tile per wave (bf16x2 split, R7-verified).
__global__ __launch_bounds__(512, 2) void hippo_main(
    const float* __restrict__ B, const float* __restrict__ C,
    const float* __restrict__ Dv, const float* __restrict__ ldt_p,
    const float* __restrict__ S16, const float* __restrict__ S32,
    const float* __restrict__ S48, const float* __restrict__ QROW,
    const float* __restrict__ Q2ROW, const float* __restrict__ Q3ROW,
    const float* __restrict__ Q4ROW, float* __restrict__ out) {
  __shared__ __align__(16) ushort_t Uh[32 * 64], Ulo[32 * 64];
  __shared__ __align__(16) ushort_t Vh[64 * 64], Vlo[64 * 64];
  const int d = blockIdx.x;
  const int tau = threadIdx.x;
  const int lane = tau & 63;
  const int w = tau >> 6;

  if (w < 4) {
    const float dt = softplus_dt(ldt_p[0]);
    const Hoist H = make_hoist(dt, lane);
    float v = lhs_solve(dt * B[d * 64 + lane], H);
    if (w == 1)      v = grow_matvec(S16, v, lane);
    else if (w == 2) v = grow_matvec(S32, v, lane);
    else if (w == 3) v = grow_matvec(S48, v, lane);
    const int j0 = w << 4;
    #pragma unroll 1
    for (int jj = 0; jj < 16; ++jj) {
      split_store(v, Vh, Vlo, j0 + jj, lane);
      if (jj < 15) v = abar_apply(v, H);
    }
  } else {
    const int i0 = w - 4;
    float u = C[d * 64 + lane];
    if (i0 == 1)      u = grow_matvec(QROW, u, lane);
    else if (i0 == 2) u = grow_matvec(Q2ROW, u, lane);
    else if (i0 == 3) u = grow_matvec(Q3ROW, u, lane);
    float pc[64];
    load_row_g(Q4ROW + lane * 64, pc);          // pc[k] = Q4[lane][k]
    #pragma unroll 1
    for (int a = 0; a < 8; ++a) {
      split_store(u, Uh, Ulo, i0 + (a << 2), lane);
      if (a < 7) u = qapply(pc, u);             // u_{i+4} = Q4 u_i
    }
  }
  __syncthreads();

  // MFMA epilogue: wave w -> i-tile (w&1), j-tile (w>>1). bf16x2 split.
  const int it = w & 1;
  const int jt = w >> 1;
  const int arow = lane & 15;
  const int kg = lane >> 4;
  f32x4 acc = {0.f, 0.f, 0.f, 0.f};
  const int ia = (it << 4) + arow;              // U row (A-frag)
  const int jv = (jt << 4) + arow;              // V row (B-frag)
  #pragma unroll
  for (int k0 = 0; k0 < 2; ++k0) {
    const int ci = (k0 << 2) + kg;              // logical chunk 0..7
    short8 ah = *(const short8*)&Uh[frag_off(ia, ci)];
    short8 al = *(const short8*)&Ulo[frag_off(ia, ci)];
    short8 bh = *(const short8*)&Vh[frag_off(jv, ci)];
    short8 bl = *(const short8*)&Vlo[frag_off(jv, ci)];
    acc = __builtin_amdgcn_mfma_f32_16x16x32_bf16(ah, bh, acc, 0, 0, 0);
    acc = __builtin_amdgcn_mfma_f32_16x16x32_bf16(al, bh, acc, 0, 0, 0);
    acc = __builtin_amdgcn_mfma_f32_16x16x32_bf16(ah, bl, acc, 0, 0, 0);
  }
  // C/D layout (m89-verified): col = lane&15, row = (lane>>4)*4 + reg.
  #pragma unroll
  for (int r = 0; r < 4; ++r) {
    const int i = (it << 4) + (kg << 2) + r;
    const int jg = (jt << 4) + arow;
    float y = acc[r];
    if (i == 0 && jg == 0) y += Dv[d];
    out[((size_t)d << 11) + (i << 6) + jg] = y;
  }
}

extern "C" void kernel_launch(void* const* d_in, const int* in_sizes, int n_in,
                              void* d_out, int out_size, void* d_ws, size_t ws_size,
                              hipStream_t stream) {
  const float* B   = (const float*)d_in[0];
  const float* C   = (const float*)d_in[1];
  const float* Dv  = (const float*)d_in[2];
  const float* ldt = (const float*)d_in[3];
  const int d_model = in_sizes[2];        // 1024
  float* S16   = (float*)d_ws;            // 16 KiB each
  float* S32   = (float*)d_ws + 4096;
  float* S48   = (float*)d_ws + 8192;
  float* QROW  = (float*)d_ws + 12288;
  float* Q2ROW = (float*)d_ws + 16384;
  float* Q3ROW = (float*)d_ws + 20480;
  float* Q4ROW = (float*)d_ws + 24576;
  hippo_pow<<<64, 64, 0, stream>>>(ldt, S16, S32, S48, QROW, Q2ROW);
  hippo_qx<<<64, 64, 0, stream>>>(QROW, Q2ROW, Q3ROW, Q4ROW);
  hippo_main<<<d_model, 512, 0, stream>>>(B, C, Dv, ldt, S16, S32, S48,
                                          QROW, Q2ROW, Q3ROW, Q4ROW,
                                          (float*)d_out);
}